// Round 2
// baseline (330.817 us; speedup 1.0000x reference)
//
#include <hip/hip_runtime.h>

#define N_NODES 100000
#define N_EDGES 1600000
#define D_IN 32
#define D_HID 16
#define D_OUT 2

#define SCAN_BLK 256
#define N_SCAN_BLKS ((N_NODES + SCAN_BLK - 1) / SCAN_BLK)   // 391

// ---------------------------------------------------------------------------
// Kernel 1: per-node dense transforms for layer 1 (+ zero the degree array).
//   xr[i]  = x[i] @ w1_rel^T            (gathered over edges later)
//   agg[i] = x[i] @ w1_root^T + b1      (accumulator pre-initialized with root)
// ---------------------------------------------------------------------------
__global__ __launch_bounds__(256) void k_node1(
    const float* __restrict__ x,
    const float* __restrict__ w_rel,    // [D_HID, D_IN]
    const float* __restrict__ w_root,   // [D_HID, D_IN]
    const float* __restrict__ b,        // [D_HID]
    float* __restrict__ xr,             // [N, D_HID]
    float* __restrict__ agg,            // [N, D_HID]
    int* __restrict__ deg)              // [N] zeroed here
{
    __shared__ float s_rel[D_HID * D_IN];
    __shared__ float s_root[D_HID * D_IN];
    __shared__ float s_b[D_HID];
    for (int i = threadIdx.x; i < D_HID * D_IN; i += blockDim.x) {
        s_rel[i]  = w_rel[i];
        s_root[i] = w_root[i];
    }
    if (threadIdx.x < D_HID) s_b[threadIdx.x] = b[threadIdx.x];
    __syncthreads();

    int node = blockIdx.x * blockDim.x + threadIdx.x;
    if (node >= N_NODES) return;
    deg[node] = 0;

    float row[D_IN];
    const float4* xp = (const float4*)(x + (size_t)node * D_IN);
#pragma unroll
    for (int i = 0; i < D_IN / 4; i++) {
        float4 v = xp[i];
        row[4*i+0] = v.x; row[4*i+1] = v.y; row[4*i+2] = v.z; row[4*i+3] = v.w;
    }

    float oa[D_HID], orr[D_HID];
#pragma unroll
    for (int o = 0; o < D_HID; o++) {
        float a = 0.f, r = s_b[o];
#pragma unroll
        for (int k = 0; k < D_IN; k++) {
            a += row[k] * s_rel[o * D_IN + k];
            r += row[k] * s_root[o * D_IN + k];
        }
        oa[o] = a; orr[o] = r;
    }

    float4* xrp  = (float4*)(xr  + (size_t)node * D_HID);
    float4* aggp = (float4*)(agg + (size_t)node * D_HID);
#pragma unroll
    for (int i = 0; i < D_HID / 4; i++) {
        xrp[i]  = make_float4(oa[4*i], oa[4*i+1], oa[4*i+2], oa[4*i+3]);
        aggp[i] = make_float4(orr[4*i], orr[4*i+1], orr[4*i+2], orr[4*i+3]);
    }
}

// ---------------------------------------------------------------------------
// CSR build step A: histogram of destination nodes.
// ---------------------------------------------------------------------------
__global__ __launch_bounds__(256) void k_hist(
    const int* __restrict__ ei, int* __restrict__ deg)
{
    int e = blockIdx.x * blockDim.x + threadIdx.x;
    if (e >= N_EDGES) return;
    atomicAdd(&deg[ei[N_EDGES + e]], 1);
}

// ---------------------------------------------------------------------------
// CSR build step B: per-block exclusive scan of deg -> row (local), bsum.
// ---------------------------------------------------------------------------
__global__ __launch_bounds__(SCAN_BLK) void k_scan1(
    const int* __restrict__ deg, int* __restrict__ row, int* __restrict__ bsum)
{
    __shared__ int s[SCAN_BLK];
    int i = blockIdx.x * SCAN_BLK + threadIdx.x;
    int v = (i < N_NODES) ? deg[i] : 0;
    s[threadIdx.x] = v;
    __syncthreads();
#pragma unroll
    for (int off = 1; off < SCAN_BLK; off <<= 1) {
        int t = (threadIdx.x >= off) ? s[threadIdx.x - off] : 0;
        __syncthreads();
        s[threadIdx.x] += t;
        __syncthreads();
    }
    int incl = s[threadIdx.x];
    if (i < N_NODES) row[i] = incl - v;          // exclusive
    if (threadIdx.x == SCAN_BLK - 1) bsum[blockIdx.x] = incl;
}

// ---------------------------------------------------------------------------
// CSR build step C: add block prefix, emit row & pos (placement cursors).
// ---------------------------------------------------------------------------
__global__ __launch_bounds__(SCAN_BLK) void k_scan2(
    int* __restrict__ row, int* __restrict__ pos, const int* __restrict__ bsum)
{
    __shared__ int s[SCAN_BLK];
    int acc = 0;
    for (int j = threadIdx.x; j < (int)blockIdx.x; j += SCAN_BLK) acc += bsum[j];
    s[threadIdx.x] = acc;
    __syncthreads();
#pragma unroll
    for (int off = SCAN_BLK / 2; off > 0; off >>= 1) {
        if (threadIdx.x < off) s[threadIdx.x] += s[threadIdx.x + off];
        __syncthreads();
    }
    int prefix = s[0];
    int i = blockIdx.x * SCAN_BLK + threadIdx.x;
    if (i < N_NODES) {
        int r = row[i] + prefix;
        row[i] = r;
        pos[i] = r;
    }
    if (blockIdx.x == 0 && threadIdx.x == 0) row[N_NODES] = N_EDGES;
}

// ---------------------------------------------------------------------------
// CSR build step D: place each edge's src into its dst bucket.
// ---------------------------------------------------------------------------
__global__ __launch_bounds__(256) void k_place(
    const int* __restrict__ ei, int* __restrict__ pos, int* __restrict__ csr_src)
{
    int e = blockIdx.x * blockDim.x + threadIdx.x;
    if (e >= N_EDGES) return;
    int src = ei[e];
    int dst = ei[N_EDGES + e];
    int slot = atomicAdd(&pos[dst], 1);
    csr_src[slot] = src;
}

// ---------------------------------------------------------------------------
// Layer-1 aggregation, pull style: agg[i][f] += sum_k xr[csr_src[k]][f].
// 16 threads per node (one per hidden feature); no atomics.
// ---------------------------------------------------------------------------
__global__ __launch_bounds__(256) void k_gather1(
    const int* __restrict__ row, const int* __restrict__ csr_src,
    const float* __restrict__ xr, float* __restrict__ agg)
{
    int t = blockIdx.x * blockDim.x + threadIdx.x;
    if (t >= N_NODES * D_HID) return;
    int node = t >> 4;
    int f = t & (D_HID - 1);
    int s0 = row[node], s1 = row[node + 1];
    float a0 = 0.f, a1 = 0.f;
    int k = s0;
    for (; k + 1 < s1; k += 2) {
        a0 += xr[csr_src[k]     * D_HID + f];
        a1 += xr[csr_src[k + 1] * D_HID + f];
    }
    if (k < s1) a0 += xr[csr_src[k] * D_HID + f];
    agg[t] += a0 + a1;   // exclusive per-thread RMW, no atomic needed
}

// ---------------------------------------------------------------------------
// Kernel: relu + per-node dense transforms for layer 2.
//   h      = relu(agg1)                 (registers only)
//   hr[i]  = h @ w2_rel^T               (gathered over edges later)
//   out[i] = h @ w2_root^T + b2         (output pre-initialized with root)
// ---------------------------------------------------------------------------
__global__ __launch_bounds__(256) void k_node2(
    const float* __restrict__ agg,      // [N, D_HID]
    const float* __restrict__ w_rel,    // [D_OUT, D_HID]
    const float* __restrict__ w_root,   // [D_OUT, D_HID]
    const float* __restrict__ b,        // [D_OUT]
    float* __restrict__ hr,             // [N, D_OUT]
    float* __restrict__ outv)           // [N, D_OUT]
{
    __shared__ float s_rel[D_OUT * D_HID];
    __shared__ float s_root[D_OUT * D_HID];
    __shared__ float s_b[D_OUT];
    for (int i = threadIdx.x; i < D_OUT * D_HID; i += blockDim.x) {
        s_rel[i]  = w_rel[i];
        s_root[i] = w_root[i];
    }
    if (threadIdx.x < D_OUT) s_b[threadIdx.x] = b[threadIdx.x];
    __syncthreads();

    int node = blockIdx.x * blockDim.x + threadIdx.x;
    if (node >= N_NODES) return;

    float h[D_HID];
    const float4* ap = (const float4*)(agg + (size_t)node * D_HID);
#pragma unroll
    for (int i = 0; i < D_HID / 4; i++) {
        float4 v = ap[i];
        h[4*i+0] = fmaxf(v.x, 0.f); h[4*i+1] = fmaxf(v.y, 0.f);
        h[4*i+2] = fmaxf(v.z, 0.f); h[4*i+3] = fmaxf(v.w, 0.f);
    }

    float o_rel[D_OUT], o_root[D_OUT];
#pragma unroll
    for (int o = 0; o < D_OUT; o++) {
        float a = 0.f, r = s_b[o];
#pragma unroll
        for (int k = 0; k < D_HID; k++) {
            a += h[k] * s_rel[o * D_HID + k];
            r += h[k] * s_root[o * D_HID + k];
        }
        o_rel[o] = a; o_root[o] = r;
    }

    ((float2*)(hr   + (size_t)node * D_OUT))[0] = make_float2(o_rel[0], o_rel[1]);
    ((float2*)(outv + (size_t)node * D_OUT))[0] = make_float2(o_root[0], o_root[1]);
}

// ---------------------------------------------------------------------------
// Layer-2 aggregation, pull style: out[i][f] += sum_k hr[csr_src[k]][f].
// 2 threads per node; hr is 0.8 MB -> L2-resident gathers; no atomics.
// ---------------------------------------------------------------------------
__global__ __launch_bounds__(256) void k_gather2(
    const int* __restrict__ row, const int* __restrict__ csr_src,
    const float* __restrict__ hr, float* __restrict__ outv)
{
    int t = blockIdx.x * blockDim.x + threadIdx.x;
    if (t >= N_NODES * D_OUT) return;
    int node = t >> 1;
    int f = t & (D_OUT - 1);
    int s0 = row[node], s1 = row[node + 1];
    float a0 = 0.f, a1 = 0.f;
    int k = s0;
    for (; k + 1 < s1; k += 2) {
        a0 += hr[csr_src[k]     * D_OUT + f];
        a1 += hr[csr_src[k + 1] * D_OUT + f];
    }
    if (k < s1) a0 += hr[csr_src[k] * D_OUT + f];
    outv[t] += a0 + a1;
}

extern "C" void kernel_launch(void* const* d_in, const int* in_sizes, int n_in,
                              void* d_out, int out_size, void* d_ws, size_t ws_size,
                              hipStream_t stream) {
    const float* x       = (const float*)d_in[0];
    const int*   ei      = (const int*)  d_in[1];
    const float* w1_rel  = (const float*)d_in[2];
    const float* w1_root = (const float*)d_in[3];
    const float* b1      = (const float*)d_in[4];
    const float* w2_rel  = (const float*)d_in[5];
    const float* w2_root = (const float*)d_in[6];
    const float* b2      = (const float*)d_in[7];
    float* out = (float*)d_out;

    // Workspace layout (~21.2 MB; everything rewritten each call):
    float* xr   = (float*)d_ws;                              // N*D_HID
    float* agg  = xr  + (size_t)N_NODES * D_HID;             // N*D_HID
    float* hr   = agg + (size_t)N_NODES * D_HID;             // N*D_OUT
    int*   deg  = (int*)(hr + (size_t)N_NODES * D_OUT);      // N
    int*   row  = deg + N_NODES;                             // N+1
    int*   pos  = row + N_NODES + 1;                         // N
    int*   bsum = pos + N_NODES;                             // N_SCAN_BLKS
    int*   csr  = bsum + N_SCAN_BLKS;                        // E

    dim3 blk(256);

    k_node1<<<dim3((N_NODES + 255) / 256), blk, 0, stream>>>(
        x, w1_rel, w1_root, b1, xr, agg, deg);

    k_hist<<<dim3((N_EDGES + 255) / 256), blk, 0, stream>>>(ei, deg);

    k_scan1<<<dim3(N_SCAN_BLKS), dim3(SCAN_BLK), 0, stream>>>(deg, row, bsum);

    k_scan2<<<dim3(N_SCAN_BLKS), dim3(SCAN_BLK), 0, stream>>>(row, pos, bsum);

    k_place<<<dim3((N_EDGES + 255) / 256), blk, 0, stream>>>(ei, pos, csr);

    k_gather1<<<dim3((N_NODES * D_HID + 255) / 256), blk, 0, stream>>>(
        row, csr, xr, agg);

    k_node2<<<dim3((N_NODES + 255) / 256), blk, 0, stream>>>(
        agg, w2_rel, w2_root, b2, hr, out);

    k_gather2<<<dim3((N_NODES * D_OUT + 255) / 256), blk, 0, stream>>>(
        row, csr, hr, out);
}

// Round 3
// 325.103 us; speedup vs baseline: 1.0176x; 1.0176x over previous
//
#include <hip/hip_runtime.h>

#define N_NODES 100000
#define N_EDGES 1600000
#define D_IN 32
#define D_HID 16
#define D_OUT 2

// Node bucketing: 128 nodes/bucket -> LDS tile 128x16 f32 (stride-17 padded).
#define NPB 128
#define NB 782                    // ceil(100000/128)
#define BIN_CHUNK 8192
#define BIN_BLOCKS ((N_EDGES + BIN_CHUNK - 1) / BIN_CHUNK)   // 196
#define HIST_CHUNK 4096
#define HIST_BLOCKS ((N_EDGES + HIST_CHUNK - 1) / HIST_CHUNK) // 391

// ---------------------------------------------------------------------------
// Kernel 1: per-node dense transforms for layer 1 (+ zero bucket histogram).
//   xr[i]  = x[i] @ w1_rel^T
//   agg[i] = x[i] @ w1_root^T + b1
// ---------------------------------------------------------------------------
__global__ __launch_bounds__(256) void k_node1(
    const float* __restrict__ x,
    const float* __restrict__ w_rel, const float* __restrict__ w_root,
    const float* __restrict__ b,
    float* __restrict__ xr, float* __restrict__ agg,
    int* __restrict__ gdeg)
{
    __shared__ float s_rel[D_HID * D_IN];
    __shared__ float s_root[D_HID * D_IN];
    __shared__ float s_b[D_HID];
    for (int i = threadIdx.x; i < D_HID * D_IN; i += blockDim.x) {
        s_rel[i]  = w_rel[i];
        s_root[i] = w_root[i];
    }
    if (threadIdx.x < D_HID) s_b[threadIdx.x] = b[threadIdx.x];
    if (blockIdx.x == 0)
        for (int i = threadIdx.x; i < NB; i += blockDim.x) gdeg[i] = 0;
    __syncthreads();

    int node = blockIdx.x * blockDim.x + threadIdx.x;
    if (node >= N_NODES) return;

    float row[D_IN];
    const float4* xp = (const float4*)(x + (size_t)node * D_IN);
#pragma unroll
    for (int i = 0; i < D_IN / 4; i++) {
        float4 v = xp[i];
        row[4*i+0] = v.x; row[4*i+1] = v.y; row[4*i+2] = v.z; row[4*i+3] = v.w;
    }

    float oa[D_HID], orr[D_HID];
#pragma unroll
    for (int o = 0; o < D_HID; o++) {
        float a = 0.f, r = s_b[o];
#pragma unroll
        for (int k = 0; k < D_IN; k++) {
            a += row[k] * s_rel[o * D_IN + k];
            r += row[k] * s_root[o * D_IN + k];
        }
        oa[o] = a; orr[o] = r;
    }

    float4* xrp  = (float4*)(xr  + (size_t)node * D_HID);
    float4* aggp = (float4*)(agg + (size_t)node * D_HID);
#pragma unroll
    for (int i = 0; i < D_HID / 4; i++) {
        xrp[i]  = make_float4(oa[4*i], oa[4*i+1], oa[4*i+2], oa[4*i+3]);
        aggp[i] = make_float4(orr[4*i], orr[4*i+1], orr[4*i+2], orr[4*i+3]);
    }
}

// ---------------------------------------------------------------------------
// Bucket histogram: LDS-reduced per block, then NB global adds per block.
// ---------------------------------------------------------------------------
__global__ __launch_bounds__(512) void k_histb(
    const int* __restrict__ ei, int* __restrict__ gdeg)
{
    __shared__ int h[NB];
    for (int i = threadIdx.x; i < NB; i += 512) h[i] = 0;
    __syncthreads();
    int e0 = blockIdx.x * HIST_CHUNK;
    int e1 = min(e0 + HIST_CHUNK, N_EDGES);
    for (int e = e0 + threadIdx.x; e < e1; e += 512)
        atomicAdd(&h[ei[N_EDGES + e] >> 7], 1);
    __syncthreads();
    for (int i = threadIdx.x; i < NB; i += 512)
        if (h[i]) atomicAdd(&gdeg[i], h[i]);
}

// ---------------------------------------------------------------------------
// Exclusive scan of the NB bucket counts (single block).
// ---------------------------------------------------------------------------
__global__ __launch_bounds__(1024) void k_scan(
    const int* __restrict__ gdeg, int* __restrict__ base, int* __restrict__ cursor)
{
    __shared__ int s[1024];
    int v = (threadIdx.x < NB) ? gdeg[threadIdx.x] : 0;
    s[threadIdx.x] = v;
    __syncthreads();
#pragma unroll
    for (int off = 1; off < 1024; off <<= 1) {
        int t = (threadIdx.x >= off) ? s[threadIdx.x - off] : 0;
        __syncthreads();
        s[threadIdx.x] += t;
        __syncthreads();
    }
    if (threadIdx.x < NB) {
        int ex = s[threadIdx.x] - v;
        base[threadIdx.x] = ex;
        cursor[threadIdx.x] = ex;
    }
    if (threadIdx.x == 0) base[NB] = N_EDGES;
}

// ---------------------------------------------------------------------------
// Bin edges into bucket-ordered record array. Per-block cursor reservation
// makes the writes sequential within each bucket (no line thrashing).
// Record: (dst&127) << 17 | src   (src < 2^17).
// ---------------------------------------------------------------------------
__global__ __launch_bounds__(512) void k_bin(
    const int* __restrict__ ei, int* __restrict__ cursor,
    unsigned int* __restrict__ recs)
{
    __shared__ int cnt[NB];
    __shared__ int loc[NB];
    __shared__ int cur[NB];
    for (int i = threadIdx.x; i < NB; i += 512) { cnt[i] = 0; cur[i] = 0; }
    __syncthreads();
    int e0 = blockIdx.x * BIN_CHUNK;
    int e1 = min(e0 + BIN_CHUNK, N_EDGES);
    for (int e = e0 + threadIdx.x; e < e1; e += 512)
        atomicAdd(&cnt[ei[N_EDGES + e] >> 7], 1);
    __syncthreads();
    for (int i = threadIdx.x; i < NB; i += 512)
        if (cnt[i] > 0) loc[i] = atomicAdd(&cursor[i], cnt[i]);
    __syncthreads();
    for (int e = e0 + threadIdx.x; e < e1; e += 512) {
        int src = ei[e];
        int dst = ei[N_EDGES + e];
        int bkt = dst >> 7;
        int idx = atomicAdd(&cur[bkt], 1);
        recs[loc[bkt] + idx] = ((unsigned)(dst & (NPB - 1)) << 17) | (unsigned)src;
    }
}

// ---------------------------------------------------------------------------
// Layer-1 accumulate: one block per bucket. 16 lanes per record gather one
// coalesced 64B line of xr[src], ds_add into the LDS tile, then one
// sequential agg += tile write. Iterations are independent (no serial chain).
// ---------------------------------------------------------------------------
__global__ __launch_bounds__(512) void k_acc1(
    const int* __restrict__ base, const unsigned int* __restrict__ recs,
    const float* __restrict__ xr, float* __restrict__ agg)
{
    __shared__ float s[NPB * 17];
    for (int i = threadIdx.x; i < NPB * 17; i += 512) s[i] = 0.f;
    __syncthreads();
    int b = blockIdx.x;
    int r0 = base[b], r1 = base[b + 1];
    int lane_r = threadIdx.x >> 4;          // 0..31 records per iteration
    int f = threadIdx.x & (D_HID - 1);
    for (int r = r0 + lane_r; r < r1; r += 32) {
        unsigned rec = recs[r];
        int src = rec & 0x1FFFF;
        int dl  = rec >> 17;
        float v = xr[src * D_HID + f];
        atomicAdd(&s[dl * 17 + f], v);      // 16 consecutive banks per record
    }
    __syncthreads();
    int nodebase = b * NPB;
    for (int t = threadIdx.x; t < NPB * D_HID; t += 512) {
        int dl = t >> 4, ff = t & (D_HID - 1);
        int node = nodebase + dl;
        if (node < N_NODES) agg[node * D_HID + ff] += s[dl * 17 + ff];
    }
}

// ---------------------------------------------------------------------------
// relu + per-node dense transforms for layer 2.
// ---------------------------------------------------------------------------
__global__ __launch_bounds__(256) void k_node2(
    const float* __restrict__ agg,
    const float* __restrict__ w_rel, const float* __restrict__ w_root,
    const float* __restrict__ b,
    float* __restrict__ hr, float* __restrict__ outv)
{
    __shared__ float s_rel[D_OUT * D_HID];
    __shared__ float s_root[D_OUT * D_HID];
    __shared__ float s_b[D_OUT];
    for (int i = threadIdx.x; i < D_OUT * D_HID; i += blockDim.x) {
        s_rel[i]  = w_rel[i];
        s_root[i] = w_root[i];
    }
    if (threadIdx.x < D_OUT) s_b[threadIdx.x] = b[threadIdx.x];
    __syncthreads();

    int node = blockIdx.x * blockDim.x + threadIdx.x;
    if (node >= N_NODES) return;

    float h[D_HID];
    const float4* ap = (const float4*)(agg + (size_t)node * D_HID);
#pragma unroll
    for (int i = 0; i < D_HID / 4; i++) {
        float4 v = ap[i];
        h[4*i+0] = fmaxf(v.x, 0.f); h[4*i+1] = fmaxf(v.y, 0.f);
        h[4*i+2] = fmaxf(v.z, 0.f); h[4*i+3] = fmaxf(v.w, 0.f);
    }

    float o_rel[D_OUT], o_root[D_OUT];
#pragma unroll
    for (int o = 0; o < D_OUT; o++) {
        float a = 0.f, r = s_b[o];
#pragma unroll
        for (int k = 0; k < D_HID; k++) {
            a += h[k] * s_rel[o * D_HID + k];
            r += h[k] * s_root[o * D_HID + k];
        }
        o_rel[o] = a; o_root[o] = r;
    }

    ((float2*)(hr   + (size_t)node * D_OUT))[0] = make_float2(o_rel[0], o_rel[1]);
    ((float2*)(outv + (size_t)node * D_OUT))[0] = make_float2(o_root[0], o_root[1]);
}

// ---------------------------------------------------------------------------
// Layer-2 accumulate: one block per bucket, 1 thread/record (8B gather of hr,
// L2/L3-resident), LDS tile 128x2, sequential out += tile.
// ---------------------------------------------------------------------------
__global__ __launch_bounds__(512) void k_acc2(
    const int* __restrict__ base, const unsigned int* __restrict__ recs,
    const float* __restrict__ hr, float* __restrict__ outv)
{
    __shared__ float s[NPB * D_OUT];
    for (int i = threadIdx.x; i < NPB * D_OUT; i += 512) s[i] = 0.f;
    __syncthreads();
    int b = blockIdx.x;
    int r0 = base[b], r1 = base[b + 1];
    for (int r = r0 + threadIdx.x; r < r1; r += 512) {
        unsigned rec = recs[r];
        int src = rec & 0x1FFFF;
        int dl  = rec >> 17;
        float2 v = *(const float2*)(hr + (size_t)src * D_OUT);
        atomicAdd(&s[dl * D_OUT + 0], v.x);
        atomicAdd(&s[dl * D_OUT + 1], v.y);
    }
    __syncthreads();
    int nodebase = b * NPB;
    for (int t = threadIdx.x; t < NPB * D_OUT; t += 512) {
        int node = nodebase + (t >> 1);
        if (node < N_NODES) outv[node * D_OUT + (t & 1)] += s[t];
    }
}

extern "C" void kernel_launch(void* const* d_in, const int* in_sizes, int n_in,
                              void* d_out, int out_size, void* d_ws, size_t ws_size,
                              hipStream_t stream) {
    const float* x       = (const float*)d_in[0];
    const int*   ei      = (const int*)  d_in[1];
    const float* w1_rel  = (const float*)d_in[2];
    const float* w1_root = (const float*)d_in[3];
    const float* b1      = (const float*)d_in[4];
    const float* w2_rel  = (const float*)d_in[5];
    const float* w2_root = (const float*)d_in[6];
    const float* b2      = (const float*)d_in[7];
    float* out = (float*)d_out;

    // Workspace layout (~20.1 MB, all rewritten each call):
    float*        xr     = (float*)d_ws;                          // N*D_HID
    float*        agg    = xr  + (size_t)N_NODES * D_HID;         // N*D_HID
    float*        hr     = agg + (size_t)N_NODES * D_HID;         // N*D_OUT
    unsigned int* recs   = (unsigned int*)(hr + (size_t)N_NODES * D_OUT); // E
    int*          gdeg   = (int*)(recs + N_EDGES);                // NB
    int*          base   = gdeg + NB;                             // NB+1
    int*          cursor = base + NB + 1;                         // NB

    k_node1<<<dim3((N_NODES + 255) / 256), dim3(256), 0, stream>>>(
        x, w1_rel, w1_root, b1, xr, agg, gdeg);

    k_histb<<<dim3(HIST_BLOCKS), dim3(512), 0, stream>>>(ei, gdeg);

    k_scan<<<dim3(1), dim3(1024), 0, stream>>>(gdeg, base, cursor);

    k_bin<<<dim3(BIN_BLOCKS), dim3(512), 0, stream>>>(ei, cursor, recs);

    k_acc1<<<dim3(NB), dim3(512), 0, stream>>>(base, recs, xr, agg);

    k_node2<<<dim3((N_NODES + 255) / 256), dim3(256), 0, stream>>>(
        agg, w2_rel, w2_root, b2, hr, out);

    k_acc2<<<dim3(NB), dim3(512), 0, stream>>>(base, recs, hr, out);
}